// Round 9
// baseline (165.562 us; speedup 1.0000x reference)
//
#include <hip/hip_runtime.h>

#define B_   8
#define C_   256
#define CI_  128
#define HW_  4096
#define HWP_ 1024

typedef short bf16x8 __attribute__((ext_vector_type(8)));
typedef float f32x4 __attribute__((ext_vector_type(4)));
typedef unsigned short u16;
typedef unsigned int u32;

// XOR swizzle for LDS reads: flips byte-offset bits 4-6 within 8-row stripes.
#define SW(row, off) ((off) ^ (((row) & 7) << 4))

__device__ __forceinline__ u32 cvtpk(float lo, float hi) {
  u32 r;
  asm("v_cvt_pk_bf16_f32 %0, %1, %2" : "=v"(r) : "v"(lo), "v"(hi));
  return r;
}
__device__ __forceinline__ f32x4 mfma16(bf16x8 a, bf16x8 b, f32x4 c) {
  return __builtin_amdgcn_mfma_f32_16x16x32_bf16(a, b, c, 0, 0, 0);
}
__device__ __forceinline__ void gl16(const void* g, void* l) {
  __builtin_amdgcn_global_load_lds(
      (const __attribute__((address_space(1))) u32*)g,
      (__attribute__((address_space(3))) u32*)l, 16, 0, 0);
}

// Stage [ROWS][64 k] bf16 tile (128B rows): LDS linear, global source
// pre-swizzled (slot^row&7) so SW() reads return natural order.
template <int ROWS>
__device__ __forceinline__ void stage_tile(const u16* src, int rstride,
                                           char* lds, int w, int lane) {
#pragma unroll
  for (int it = 0; it < ROWS / 32; ++it) {
    int L = it * 256 + w * 64 + lane;
    int row = L >> 3, slot = L & 7;
    gl16(src + (size_t)row * rstride + ((slot ^ (row & 7)) << 3),
         lds + it * 4096 + w * 1024);
  }
}
// Stage [64 rows][128 c] bf16 tile (256B rows).
__device__ __forceinline__ void stage_tile256(const u16* src, char* lds, int w, int lane) {
#pragma unroll
  for (int it = 0; it < 4; ++it) {
    int L = it * 256 + w * 64 + lane;
    int row = L >> 4, slot = L & 15;
    gl16(src + (size_t)row * 128 + ((slot ^ (row & 7)) << 3),
         lds + it * 4096 + w * 1024);
  }
}
// Stage [64 rows][256 k] bf16 tile (512B rows).
__device__ __forceinline__ void stage512(const u16* src, char* lds, int w, int lane) {
#pragma unroll
  for (int it = 0; it < 8; ++it) {
    int L = it * 256 + w * 64 + lane;
    int row = L >> 5, slot = L & 31;
    gl16(src + (size_t)row * 256 + ((slot ^ (row & 7)) << 3),
         lds + it * 4096 + w * 1024);
  }
}

// ---------------------------------------------------------------------------
// prep: x fp32 -> x_t bf16 [b][4096][256] + 2x2-maxpool xp_t [b][1024][256].
// Extra blocks (p==32, y==0, z<4) convert the 4 weight matrices to bf16.
__global__ __launch_bounds__(256) void prep(const float* __restrict__ x,
                                            u16* __restrict__ xt,
                                            u16* __restrict__ xpt,
                                            const float* __restrict__ w0,
                                            const float* __restrict__ w1,
                                            const float* __restrict__ w2,
                                            const float* __restrict__ w3,
                                            u16* __restrict__ wB) {
  const int b = blockIdx.z, p = blockIdx.x;
  const int t = threadIdx.x;
  if (p == 32) {
    if (blockIdx.y == 0 && b < 4) {
      const float* src = (b == 0) ? w0 : (b == 1) ? w1 : (b == 2) ? w2 : w3;
      u16* dst = wB + b * 32768;
      for (int i = t * 8; i < 32768; i += 2048) {
        float4 a = *(const float4*)&src[i];
        float4 c = *(const float4*)&src[i + 4];
        uint4 v;
        v.x = cvtpk(a.x, a.y);
        v.y = cvtpk(a.z, a.w);
        v.z = cvtpk(c.x, c.y);
        v.w = cvtpk(c.z, c.w);
        *(uint4*)&dst[i] = v;
      }
    }
    return;
  }
  __shared__ __align__(16) char sm[16384];  // [128 n][64 c] bf16, 8B-granule rotate
  const int c0 = blockIdx.y * 64;
#pragma unroll
  for (int k = 0; k < 2; ++k) {
    int pi = k * 256 + t;
    int ng = pi & 31, cg = pi >> 5;
    float4 v[4];
#pragma unroll
    for (int cc = 0; cc < 4; ++cc)
      v[cc] = *(const float4*)&x[((size_t)(b * C_ + c0 + cg * 4 + cc)) * HW_ + p * 128 + ng * 4];
#pragma unroll
    for (int jj = 0; jj < 4; ++jj) {
      int n = ng * 4 + jj;
      uint2 pk;
      pk.x = cvtpk(v[0][jj], v[1][jj]);
      pk.y = cvtpk(v[2][jj], v[3][jj]);
      int slot = (cg + ng) & 15;
      *(uint2*)(sm + n * 128 + slot * 8) = pk;
    }
  }
  __syncthreads();
#pragma unroll
  for (int it = 0; it < 4; ++it) {  // x_t
    int L = it * 256 + t;
    int row = L >> 3, ch = L & 7;
    int s0 = (2 * ch + (row >> 2)) & 15, s1 = (2 * ch + 1 + (row >> 2)) & 15;
    uint2 a = *(const uint2*)(sm + row * 128 + s0 * 8);
    uint2 bb = *(const uint2*)(sm + row * 128 + s1 * 8);
    uint4 o = {a.x, a.y, bb.x, bb.y};
    *(uint4*)(xt + ((size_t)(b * HW_ + p * 128 + row)) * C_ + c0 + ch * 8) = o;
  }
#pragma unroll
  for (int k = 0; k < 2; ++k) {  // pool (bf16 max: rounding monotone => exact)
    int cg = t & 15, mw = (t >> 4) + k * 16;
    int rows[4] = {2 * mw, 2 * mw + 1, 64 + 2 * mw, 65 + 2 * mw};
    uint2 rv[4];
#pragma unroll
    for (int r = 0; r < 4; ++r) {
      int n = rows[r];
      int slot = (cg + (n >> 2)) & 15;
      rv[r] = *(const uint2*)(sm + n * 128 + slot * 8);
    }
    u16 outc[4];
#pragma unroll
    for (int ci = 0; ci < 4; ++ci) {
      float m = -1e30f;
#pragma unroll
      for (int r = 0; r < 4; ++r) {
        u32 word = (ci < 2) ? rv[r].x : rv[r].y;
        u16 h = (u16)((ci & 1) ? (word >> 16) : (word & 0xffff));
        m = fmaxf(m, __builtin_bit_cast(float, (u32)h << 16));
      }
      outc[ci] = (u16)(__builtin_bit_cast(u32, m) >> 16);
    }
    uint2 pk;
    pk.x = (u32)outc[0] | ((u32)outc[1] << 16);
    pk.y = (u32)outc[2] | ((u32)outc[3] << 16);
    *(uint2*)(xpt + ((size_t)(b * HWP_ + p * 32 + mw)) * C_ + c0 + cg * 4) = pk;
  }
}

// ---------------------------------------------------------------------------
// GEMM A=W (bf16): out_t[b][n][o] = sum_k W[o][k]*act_t[b][n][k] + bias[o]
__global__ __launch_bounds__(256) void gemm_wa(const u16* __restrict__ Wb,
                                               const u16* __restrict__ act,
                                               const float* __restrict__ bias,
                                               u16* __restrict__ outp,
                                               int Ntok) {
  __shared__ __align__(16) char smem[65536];
  const int b = blockIdx.y;
  const int n0 = blockIdx.x * 128;
  const int t = threadIdx.x, lane = t & 63, w = t >> 6;
  const int lr = lane & 15, lg = lane >> 4;
  const int otb = (w & 1) * 4, ntb = (w >> 1) * 4;
  const u16* actb = act + (size_t)(b * Ntok + n0) * 256;
  f32x4 acc[4][4];
#pragma unroll
  for (int i = 0; i < 4; ++i)
#pragma unroll
    for (int j = 0; j < 4; ++j) acc[i][j] = (f32x4){0.f, 0.f, 0.f, 0.f};

  stage_tile<128>(Wb, 256, smem, w, lane);
  stage_tile<128>(actb, 256, smem + 16384, w, lane);
  for (int kc = 0; kc < 4; ++kc) {
    __syncthreads();
    if (kc < 3) {
      char* nb = smem + ((kc + 1) & 1) * 32768;
      stage_tile<128>(Wb + (kc + 1) * 64, 256, nb, w, lane);
      stage_tile<128>(actb + (kc + 1) * 64, 256, nb + 16384, w, lane);
    }
    char* Ws = smem + (kc & 1) * 32768;
    char* Xs = Ws + 16384;
#pragma unroll
    for (int ks = 0; ks < 2; ++ks) {
      bf16x8 af[4], bfr[4];
#pragma unroll
      for (int i = 0; i < 4; ++i) {
        int rA = (otb + i) * 16 + lr;
        af[i] = *(const bf16x8*)(Ws + rA * 128 + SW(rA, ks * 64 + lg * 16));
        int rB = (ntb + i) * 16 + lr;
        bfr[i] = *(const bf16x8*)(Xs + rB * 128 + SW(rB, ks * 64 + lg * 16));
      }
#pragma unroll
      for (int i = 0; i < 4; ++i)
#pragma unroll
        for (int j = 0; j < 4; ++j) acc[i][j] = mfma16(af[i], bfr[j], acc[i][j]);
    }
  }
#pragma unroll
  for (int i = 0; i < 4; ++i) {
    int obase = (otb + i) * 16 + lg * 4;
    float b0 = bias[obase], b1 = bias[obase + 1], b2 = bias[obase + 2], b3 = bias[obase + 3];
#pragma unroll
    for (int j = 0; j < 4; ++j) {
      int n = (ntb + j) * 16 + lr;
      f32x4 v = acc[i][j];
      uint2 pk;
      pk.x = cvtpk(v[0] + b0, v[1] + b1);
      pk.y = cvtpk(v[2] + b2, v[3] + b3);
      *(uint2*)(smem + n * 256 + SW(n, obase * 2)) = pk;
    }
  }
  __syncthreads();
#pragma unroll
  for (int it = 0; it < 8; ++it) {
    int L = it * 256 + t;
    int row = L >> 4, ch = L & 15;
    uint4 v = *(const uint4*)(smem + row * 256 + SW(row, ch * 16));
    *(uint4*)(outp + ((size_t)b * Ntok + n0 + row) * 128 + ch * 8) = v;
  }
}

// ---------------------------------------------------------------------------
// GEMM A=act (bf16 W): out[b][o][m] = sum_k act_t[b][m][k]*W[o][k] + bias[o]
template <int KD>
__global__ __launch_bounds__(256) void gemm_aw(const u16* __restrict__ act,
                                               const u16* __restrict__ Wb,
                                               const float* __restrict__ bias,
                                               u16* __restrict__ outp,
                                               int Mtok, int O) {
  __shared__ __align__(16) char smem[49152];
  const int b = blockIdx.z;
  const int m0 = blockIdx.x * 64;
  const int o0 = blockIdx.y * 128;
  const int t = threadIdx.x, lane = t & 63, w = t >> 6;
  const int lr = lane & 15, lg = lane >> 4;
  const int otb = w * 2;
  const u16* actb = act + (size_t)(b * Mtok + m0) * KD;
  const u16* Wbb = Wb + (size_t)o0 * KD;
  constexpr int NCH = KD / 64;
  f32x4 acc[4][2];
#pragma unroll
  for (int i = 0; i < 4; ++i)
#pragma unroll
    for (int j = 0; j < 2; ++j) acc[i][j] = (f32x4){0.f, 0.f, 0.f, 0.f};

  stage_tile<64>(actb, KD, smem, w, lane);
  stage_tile<128>(Wbb, KD, smem + 8192, w, lane);
  for (int kc = 0; kc < NCH; ++kc) {
    __syncthreads();
    if (kc < NCH - 1) {
      char* nb = smem + ((kc + 1) & 1) * 24576;
      stage_tile<64>(actb + (kc + 1) * 64, KD, nb, w, lane);
      stage_tile<128>(Wbb + (kc + 1) * 64, KD, nb + 8192, w, lane);
    }
    char* As = smem + (kc & 1) * 24576;
    char* Bs = As + 8192;
#pragma unroll
    for (int ks = 0; ks < 2; ++ks) {
      bf16x8 af[4], bfr[2];
#pragma unroll
      for (int i = 0; i < 4; ++i) {
        int r = i * 16 + lr;
        af[i] = *(const bf16x8*)(As + r * 128 + SW(r, ks * 64 + lg * 16));
      }
#pragma unroll
      for (int j = 0; j < 2; ++j) {
        int r = (otb + j) * 16 + lr;
        bfr[j] = *(const bf16x8*)(Bs + r * 128 + SW(r, ks * 64 + lg * 16));
      }
#pragma unroll
      for (int i = 0; i < 4; ++i)
#pragma unroll
        for (int j = 0; j < 2; ++j) acc[i][j] = mfma16(af[i], bfr[j], acc[i][j]);
    }
  }
#pragma unroll
  for (int j = 0; j < 2; ++j) {
    int o = (otb + j) * 16 + lr;
    float bi = bias[o0 + o];
#pragma unroll
    for (int i = 0; i < 4; ++i) {
      int mq = i * 16 + lg * 4;
      f32x4 v = acc[i][j];
      uint2 pk;
      pk.x = cvtpk(v[0] + bi, v[1] + bi);
      pk.y = cvtpk(v[2] + bi, v[3] + bi);
      *(uint2*)(smem + o * 128 + SW(o, mq * 2)) = pk;
    }
  }
  __syncthreads();
#pragma unroll
  for (int it = 0; it < 4; ++it) {
    int L = it * 256 + t;
    int row = L >> 3, ch = L & 7;
    uint4 v = *(const uint4*)(smem + row * 128 + SW(row, ch * 16));
    *(uint4*)(outp + ((size_t)b * O + o0 + row) * Mtok + m0 + ch * 8) = v;
  }
}

// ---------------------------------------------------------------------------
// mega_attn: Q-GEMM + flash attention + z-GEMM + BN partials.
// Phase B sync (conservative, r7 structure + internal barrier):
//   - K double-buffered: staged at tile start, drained by the INTERNAL barrier
//     of the same tile, consumed next tile.
//   - V single-buffered: staged after the end-of-tile barrier, drained by the
//     next tile's INTERNAL barrier (between QK/P-write and PV) before use.
// Every stage->consume and consume->overwrite edge crosses a __syncthreads
// (which drains vmcnt/lgkmcnt for all waves). No counted vmcnt, no inline-asm
// waits — the internal barrier also orders the P LDS write->read.
#define ATTN_TILE(KCP)                                                        \
  {                                                                           \
    const char* Kc = (KCP);                                                   \
    int rn = w * 16 + lr;                                                     \
    _Pragma("unroll")                                                         \
    for (int mt = 0; mt < 4; ++mt) {                                          \
      f32x4 s = {0.f, 0.f, 0.f, 0.f};                                         \
      _Pragma("unroll")                                                       \
      for (int kq = 0; kq < 4; ++kq) {                                        \
        int r = mt * 16 + lr;                                                 \
        bf16x8 a = *(const bf16x8*)(Kc + r * 256 + SW(r, kq * 64 + lg * 16)); \
        s = mfma16(a, qf[kq], s);                                             \
      }                                                                       \
      float p0 = __expf(s[0] * scale), p1 = __expf(s[1] * scale);             \
      float p2 = __expf(s[2] * scale), p3 = __expf(s[3] * scale);             \
      csum += (p0 + p1) + (p2 + p3);                                          \
      uint2 pk;                                                               \
      pk.x = cvtpk(p0, p1);                                                   \
      pk.y = cvtpk(p2, p3);                                                   \
      *(uint2*)(Pn + rn * 128 + SW(rn, mt * 32 + lg * 8)) = pk;               \
    }                                                                         \
    __syncthreads(); /* P visible; this tile's V (and next K) fully landed */ \
    bf16x8 pb0 = *(const bf16x8*)(Pn + rn * 128 + SW(rn, lg * 16));           \
    bf16x8 pb1 = *(const bf16x8*)(Pn + rn * 128 + SW(rn, 64 + lg * 16));      \
    _Pragma("unroll")                                                         \
    for (int ct = 0; ct < 8; ++ct) {                                          \
      int rc = ct * 16 + lr;                                                  \
      bf16x8 a0 = *(const bf16x8*)(Vs + rc * 128 + SW(rc, lg * 16));          \
      bf16x8 a1 = *(const bf16x8*)(Vs + rc * 128 + SW(rc, 64 + lg * 16));     \
      accT[ct] = mfma16(a0, pb0, accT[ct]);                                   \
      accT[ct] = mfma16(a1, pb1, accT[ct]);                                   \
    }                                                                         \
  }

__global__ __launch_bounds__(256, 2) void mega_attn(
    const u16* __restrict__ xt, const u16* __restrict__ thW,
    const float* __restrict__ thB, const u16* __restrict__ Kt,
    const u16* __restrict__ Vn, const u16* __restrict__ wzW,
    const float* __restrict__ wzB, float* __restrict__ zf,
    float* __restrict__ sums, float* __restrict__ sqs) {
  __shared__ __align__(16) char smem[73728];
  char* Qs = smem;            // 16K: Q -> t
  char* KD = smem + 16384;    // 32K: x-tile / K dbuf / wz chunk
  char* Vs = smem + 49152;    // 16K: thW chunk / V
  char* Pn = smem + 65536;    // 8K:  P (wave-private rows)
  const int bid = blockIdx.x;
  const int swz = (bid & 7) * 64 + (bid >> 3);  // XCD-bijective (512 % 8 == 0)
  const int b = swz >> 6, n0 = (swz & 63) * 64;
  const int t = threadIdx.x, lane = t & 63, w = t >> 6;
  const int lr = lane & 15, lg = lane >> 4;
  const float scale = 0.08838834764831845f;  // 128^-0.5
  const u16* Kbase = Kt + (size_t)b * HWP_ * 128;
  const u16* Vbase = Vn + (size_t)b * 128 * HWP_;

  // ---- Phase A: Q = x_t(64x256) . theta_w^T (128x256) + theta_b ----
  stage512(xt + (size_t)(b * HW_ + n0) * 256, KD, w, lane);
  stage_tile<128>(thW, 256, Vs, w, lane);
  f32x4 qacc[2][4];
#pragma unroll
  for (int i = 0; i < 2; ++i)
#pragma unroll
    for (int j = 0; j < 4; ++j) qacc[i][j] = (f32x4){0.f, 0.f, 0.f, 0.f};
  for (int kc = 0; kc < 4; ++kc) {
    __syncthreads();  // drains staged chunk (and x-tile on kc=0)
#pragma unroll
    for (int ks = 0; ks < 2; ++ks) {
      bf16x8 af[2], bx[4];
#pragma unroll
      for (int oi = 0; oi < 2; ++oi) {
        int rA = w * 32 + oi * 16 + lr;
        af[oi] = *(const bf16x8*)(Vs + rA * 128 + SW(rA, ks * 64 + lg * 16));
      }
#pragma unroll
      for (int nj = 0; nj < 4; ++nj) {
        int rB = nj * 16 + lr;
        bx[nj] = *(const bf16x8*)(KD + rB * 512 + SW(rB, kc * 128 + ks * 64 + lg * 16));
      }
#pragma unroll
      for (int oi = 0; oi < 2; ++oi)
#pragma unroll
        for (int nj = 0; nj < 4; ++nj)
          qacc[oi][nj] = mfma16(af[oi], bx[nj], qacc[oi][nj]);
    }
    __syncthreads();  // all waves done with Vs chunk
    if (kc < 3) stage_tile<128>(thW + (kc + 1) * 64, 256, Vs, w, lane);
  }
  // epilogue: Q -> Qs [64 n][128 c] (+bias, bf16)
#pragma unroll
  for (int oi = 0; oi < 2; ++oi) {
    int ob = w * 32 + oi * 16 + lg * 4;
    float b0 = thB[ob], b1 = thB[ob + 1], b2 = thB[ob + 2], b3 = thB[ob + 3];
#pragma unroll
    for (int nj = 0; nj < 4; ++nj) {
      int n = nj * 16 + lr;
      f32x4 v = qacc[oi][nj];
      uint2 pk;
      pk.x = cvtpk(v[0] + b0, v[1] + b1);
      pk.y = cvtpk(v[2] + b2, v[3] + b3);
      *(uint2*)(Qs + n * 256 + SW(n, ob * 2)) = pk;
    }
  }
  __syncthreads();  // Q visible; KD/Vs free

  // ---- Phase B: flash attention ----
  stage_tile256(Kbase, KD, w, lane);             // K0 -> KD buf0
  stage_tile<128>(Vbase, HWP_, Vs, w, lane);     // V0
  bf16x8 qf[4];
  {
    int rq = w * 16 + lr;
#pragma unroll
    for (int kq = 0; kq < 4; ++kq)
      qf[kq] = *(const bf16x8*)(Qs + rq * 256 + SW(rq, kq * 64 + lg * 16));
  }
  f32x4 accT[8];
#pragma unroll
  for (int ct = 0; ct < 8; ++ct) accT[ct] = (f32x4){0.f, 0.f, 0.f, 0.f};
  float csum = 0.f;
  __syncthreads();  // K0/V0 landed (all waves drained)

  for (int tt = 0; tt < 15; ++tt) {
    // K[tt+1] -> other K buffer; drained by ATTN_TILE(tt)'s internal barrier
    stage_tile256(Kbase + (size_t)(tt + 1) * 64 * 128,
                  KD + ((tt + 1) & 1) * 16384, w, lane);
    ATTN_TILE(KD + (tt & 1) * 16384);
    __syncthreads();  // all waves done with V[tt] (and K[tt])
    // V[tt+1] -> Vs; drained by ATTN_TILE(tt+1)'s internal barrier
    stage_tile<128>(Vbase + (tt + 1) * 64, HWP_, Vs, w, lane);
  }
  ATTN_TILE(KD + 16384);  // tile 15: K in buf1

  csum += __shfl_xor(csum, 16);
  csum += __shfl_xor(csum, 32);
  float rinv = 1.f / csum;
  // pack t -> Qs [64 n][128 c] bf16 (wave-private rows; laggard waves are past
  // the tile-15 internal barrier, so no wave still reads Qs)
  {
    int rn = w * 16 + lr;
#pragma unroll
    for (int ct = 0; ct < 8; ++ct) {
      f32x4 v = accT[ct];
      uint2 pk;
      pk.x = cvtpk(v[0] * rinv, v[1] * rinv);
      pk.y = cvtpk(v[2] * rinv, v[3] * rinv);
      *(uint2*)(Qs + rn * 256 + SW(rn, ct * 32 + lg * 8)) = pk;
    }
  }
  __syncthreads();  // t visible; KD free

  // ---- Phase C: z = t(64x128) . wz^T (256x128) + wz_b; BN partials ----
  f32x4 zacc[4][4];
#pragma unroll
  for (int i = 0; i < 4; ++i)
#pragma unroll
    for (int j = 0; j < 4; ++j) zacc[i][j] = (f32x4){0.f, 0.f, 0.f, 0.f};
  for (int kc = 0; kc < 2; ++kc) {
    stage_tile<256>(wzW + kc * 64, 128, KD, w, lane);  // [256 o][64 k]
    __syncthreads();
#pragma unroll
    for (int ks = 0; ks < 2; ++ks) {
      bf16x8 at[4], bw[4];
#pragma unroll
      for (int ni = 0; ni < 4; ++ni) {
        int rt = ni * 16 + lr;
        at[ni] = *(const bf16x8*)(Qs + rt * 256 + SW(rt, kc * 128 + ks * 64 + lg * 16));
      }
#pragma unroll
      for (int oj = 0; oj < 4; ++oj) {
        int ro = w * 64 + oj * 16 + lr;
        bw[oj] = *(const bf16x8*)(KD + ro * 128 + SW(ro, ks * 64 + lg * 16));
      }
#pragma unroll
      for (int ni = 0; ni < 4; ++ni)
#pragma unroll
        for (int oj = 0; oj < 4; ++oj)
          zacc[ni][oj] = mfma16(at[ni], bw[oj], zacc[ni][oj]);
    }
    __syncthreads();  // all waves done with KD chunk
  }
  // bias + BN partials (sum over this block's 64 tokens per channel)
  float bz[4];
#pragma unroll
  for (int oj = 0; oj < 4; ++oj) bz[oj] = wzB[w * 64 + oj * 16 + lr];
#pragma unroll
  for (int oj = 0; oj < 4; ++oj) {
    float s = 0.f, q = 0.f;
#pragma unroll
    for (int ni = 0; ni < 4; ++ni) {
      f32x4 v = zacc[ni][oj];
#pragma unroll
      for (int r = 0; r < 4; ++r) {
        float vv = v[r] + bz[oj];
        s += vv;
        q += vv * vv;
      }
    }
    s += __shfl_xor(s, 16); q += __shfl_xor(q, 16);
    s += __shfl_xor(s, 32); q += __shfl_xor(q, 32);
    if (lg == 0) {
      int o = w * 64 + oj * 16 + lr;
      sums[(size_t)o * 512 + swz] = s;
      sqs[(size_t)o * 512 + swz] = q;
    }
  }
  // z -> global fp32 [b][o][n], direct from registers
#pragma unroll
  for (int oj = 0; oj < 4; ++oj) {
    int o = w * 64 + oj * 16 + lr;
    float* dst = zf + ((size_t)(b * C_ + o)) * HW_ + n0;
#pragma unroll
    for (int ni = 0; ni < 4; ++ni) {
      f32x4 v = zacc[ni][oj];
      f32x4 vb = {v[0] + bz[oj], v[1] + bz[oj], v[2] + bz[oj], v[3] + bz[oj]};
      *(f32x4*)(dst + ni * 16 + lg * 4) = vb;
    }
  }
}

// ---------------------------------------------------------------------------
__global__ __launch_bounds__(256) void bn_finalize(const float* __restrict__ sums,
                                                   const float* __restrict__ sqs,
                                                   float* __restrict__ stats) {
  __shared__ float s1[256], s2[256];
  const int c = blockIdx.x, t = threadIdx.x;
  float a = sums[(size_t)c * 512 + t] + sums[(size_t)c * 512 + 256 + t];
  float q = sqs[(size_t)c * 512 + t] + sqs[(size_t)c * 512 + 256 + t];
  s1[t] = a;
  s2[t] = q;
  __syncthreads();
  for (int st = 128; st > 0; st >>= 1) {
    if (t < st) {
      s1[t] += s1[t + st];
      s2[t] += s2[t + st];
    }
    __syncthreads();
  }
  if (t == 0) {
    const float inv = 1.f / (float)(B_ * HW_);
    float mean = s1[0] * inv;
    float var = s2[0] * inv - mean * mean;
    stats[c] = mean;
    stats[C_ + c] = rsqrtf(var + 1e-5f);
  }
}

// out = x + gamma*(z-mean)*invstd + beta (float4, fp32 z)
__global__ __launch_bounds__(256) void final4(const float4* __restrict__ x,
                                              const float4* __restrict__ z,
                                              const float* __restrict__ stats,
                                              const float* __restrict__ gamma,
                                              const float* __restrict__ beta,
                                              float4* __restrict__ out) {
  size_t i = (size_t)blockIdx.x * 256 + threadIdx.x;  // over 2,097,152 float4
  int c = (int)((i >> 10) & 255);
  float ga = gamma[c] * stats[C_ + c];
  float be = beta[c] - stats[c] * ga;
  float4 xv = x[i], zv = z[i], o;
  o.x = fmaf(zv.x, ga, xv.x + be);
  o.y = fmaf(zv.y, ga, xv.y + be);
  o.z = fmaf(zv.z, ga, xv.z + be);
  o.w = fmaf(zv.w, ga, xv.w + be);
  out[i] = o;
}

// ---------------------------------------------------------------------------
extern "C" void kernel_launch(void* const* d_in, const int* in_sizes, int n_in,
                              void* d_out, int out_size, void* d_ws, size_t ws_size,
                              hipStream_t stream) {
  const float* x        = (const float*)d_in[0];
  const float* theta_w  = (const float*)d_in[1];
  const float* theta_b  = (const float*)d_in[2];
  const float* phi_w    = (const float*)d_in[3];
  const float* phi_b    = (const float*)d_in[4];
  const float* g_w      = (const float*)d_in[5];
  const float* g_b      = (const float*)d_in[6];
  const float* wz_w     = (const float*)d_in[7];
  const float* wz_b     = (const float*)d_in[8];
  const float* bn_gamma = (const float*)d_in[9];
  const float* bn_beta  = (const float*)d_in[10];
  float* out = (float*)d_out;

  char* ws = (char*)d_ws;
  u16* x_t     = (u16*)(ws);                  // 16 MB
  u16* xp_t    = (u16*)(ws + 16777216);       //  4 MB
  u16* phi_t   = (u16*)(ws + 20971520);       //  2 MB
  u16* g_nat   = (u16*)(ws + 23068672);       //  2 MB
  float* zf    = (float*)(ws + 25165824);     // 33.5 MB (fp32 z)
  float* stats = (float*)(ws + 58720256);     //  2 KB
  float* bsums = (float*)(ws + 58722304);     // 512 KB
  float* bsqs  = (float*)(ws + 59246592);     // 512 KB
  u16* wB      = (u16*)(ws + 59770880);       // 256 KB

  prep<<<dim3(33, 4, 8), 256, 0, stream>>>(x, x_t, xp_t, theta_w, phi_w, g_w, wz_w, wB);
  gemm_wa<<<dim3(8, 8), 256, 0, stream>>>(wB + 32768, xp_t, phi_b, phi_t, HWP_);
  gemm_aw<256><<<dim3(16, 1, 8), 256, 0, stream>>>(xp_t, wB + 65536, g_b, g_nat, HWP_, 128);
  mega_attn<<<dim3(512), 256, 0, stream>>>(x_t, wB, theta_b, phi_t, g_nat,
                                           wB + 98304, wz_b, zf, bsums, bsqs);
  bn_finalize<<<256, 256, 0, stream>>>(bsums, bsqs, stats);
  final4<<<8192, 256, 0, stream>>>((const float4*)x, (const float4*)zf, stats,
                                   bn_gamma, bn_beta, (float4*)out);
}